// Round 7
// baseline (1212.879 us; speedup 1.0000x reference)
//
#include <hip/hip_runtime.h>
#include <cstdint>

#define NH 12
#define CC 768
#define NN 1025
#define BB 16
#define HW 32
#define MPAD 16512   // 129*128 padded rows
#define MV 16400     // valid rows (B*N)
#define GM 8         // supertile rows for L2 raster

typedef _Float16 f16;
typedef _Float16 f16x4 __attribute__((ext_vector_type(4)));
typedef _Float16 f16x8 __attribute__((ext_vector_type(8)));
typedef float    f32x4 __attribute__((ext_vector_type(4)));

__device__ __forceinline__ f16 hi_part(float x) { return (f16)x; }
__device__ __forceinline__ f16 lo_part(float x) { f16 h = (f16)x; return (f16)(x - (float)h); }

__device__ __forceinline__ void gload16(const f16* g, f16* l) {
    __builtin_amdgcn_global_load_lds((const __attribute__((address_space(1))) void*)g,
                                     (__attribute__((address_space(3))) void*)l, 16, 0, 0);
}

// ---------- pack A (GEMM1 input): fused CPE depthwise-3x3 + residual -> fp16 hi or lo ----------
template<int LO>
__global__ __launch_bounds__(192) void packA_cpe(const float* __restrict__ in,
                                                 const float* __restrict__ w,
                                                 const float* __restrict__ bias,
                                                 f16* __restrict__ Ah) {
    int m = blockIdx.x;              // padded row 0..16511
    int t = threadIdx.x;
    int c = t * 4;
    f16x4 o = {(f16)0, (f16)0, (f16)0, (f16)0};
    if (m < MV) {
        int b = m / NN, n = m % NN;
        float4 acc;
        if (n == 0) {
            acc = *(const float4*)(in + (size_t)m * CC + c);   // cls token: copy
        } else {
            int p = n - 1, y = p >> 5, x = p & 31;
            acc = *(const float4*)(bias + c);
            float4 ctr = *(const float4*)(in + (size_t)m * CC + c);
            acc.x += ctr.x; acc.y += ctr.y; acc.z += ctr.z; acc.w += ctr.w;  // residual
            #pragma unroll
            for (int ky = 0; ky < 3; ++ky) {
                int yy = y + ky - 1;
                if (yy < 0 || yy >= HW) continue;
                #pragma unroll
                for (int kx = 0; kx < 3; ++kx) {
                    int xx = x + kx - 1;
                    if (xx < 0 || xx >= HW) continue;
                    float4 wv = *(const float4*)(w + (size_t)(ky*3+kx)*CC + c);
                    float4 iv = *(const float4*)(in + ((size_t)(b*NN) + 1 + yy*HW + xx)*CC + c);
                    acc.x = fmaf(wv.x, iv.x, acc.x);
                    acc.y = fmaf(wv.y, iv.y, acc.y);
                    acc.z = fmaf(wv.z, iv.z, acc.z);
                    acc.w = fmaf(wv.w, iv.w, acc.w);
                }
            }
        }
        if (LO) { o[0]=lo_part(acc.x); o[1]=lo_part(acc.y); o[2]=lo_part(acc.z); o[3]=lo_part(acc.w); }
        else    { o[0]=hi_part(acc.x); o[1]=hi_part(acc.y); o[2]=hi_part(acc.z); o[3]=hi_part(acc.w); }
    }
    *(f16x4*)&Ah[(size_t)m * CC + c] = o;
}

// ---------- pack A (GEMM2 input): attention output lives in qkv k-columns ----------
template<int LO>
__global__ __launch_bounds__(192) void packA_attn(const float* __restrict__ qkv,
                                                  f16* __restrict__ Ah) {
    int m = blockIdx.x;
    int t = threadIdx.x;
    int c = t * 4;
    f16x4 o = {(f16)0, (f16)0, (f16)0, (f16)0};
    if (m < MV) {
        float4 v = *(const float4*)&qkv[(size_t)m * 2304 + 768 + c];
        if (LO) { o[0]=lo_part(v.x); o[1]=lo_part(v.y); o[2]=lo_part(v.z); o[3]=lo_part(v.w); }
        else    { o[0]=hi_part(v.x); o[1]=hi_part(v.y); o[2]=hi_part(v.z); o[3]=hi_part(v.w); }
    }
    *(f16x4*)&Ah[(size_t)m * CC + c] = o;
}

// ---------- pack B^T: W[768][Nc] fp32 -> Bt[Nc][1536] fp16, [n][0:768]=hi, [n][768:1536]=lo ----------
__global__ __launch_bounds__(256) void packBT(const float* __restrict__ W,
                                              f16* __restrict__ Bt, int Nc) {
    __shared__ float tile[32][33];
    int k0 = blockIdx.x * 32, n0 = blockIdx.y * 32;
    int t = threadIdx.x;
    int ty = t >> 3, tx4 = (t & 7) << 2;
    float4 v = *(const float4*)&W[(size_t)(k0 + ty) * Nc + n0 + tx4];
    tile[ty][tx4+0] = v.x; tile[ty][tx4+1] = v.y; tile[ty][tx4+2] = v.z; tile[ty][tx4+3] = v.w;
    __syncthreads();
    int nl = ty, kl = tx4;
    f16x4 oh, ol;
    #pragma unroll
    for (int i = 0; i < 4; ++i) {
        float x = tile[kl + i][nl];
        f16 h = (f16)x;
        oh[i] = h;
        ol[i] = (f16)(x - (float)h);
    }
    size_t base = (size_t)(n0 + nl) * 1536 + (k0 + kl);
    *(f16x4*)&Bt[base]       = oh;
    *(f16x4*)&Bt[base + 768] = ol;
}

// ---------- MFMA GEMM: C[MV][Nc] (=|+=) A[MPAD][768] x Bt-sections, 128x128 tile ----------
// 1-D grid with XCD-bijective swizzle + GM-row supertile raster (col-fastest).
// global_load_lds(16B) staging, 2-deep LDS double buffer.
template<int ACC>
__global__ __launch_bounds__(256) void gemm_mfma(const f16* __restrict__ A,
                                                 const f16* __restrict__ Bt,
                                                 const float* __restrict__ bias,
                                                 float* __restrict__ C,
                                                 int Nc, int nsteps, int boff1) {
    __shared__ f16 lds[16384];     // As0[128][32] | Bs0 | As1 | Bs1 (4096 f16 each)
    int t = threadIdx.x;
    int w = t >> 6, l = t & 63;

    // --- raster decode ---
    int nwg = gridDim.x;
    int ntn = Nc >> 7;
    int ntm = nwg / ntn;
    int q8 = nwg >> 3, r8 = nwg & 7;
    int xcd = blockIdx.x & 7, lin = blockIdx.x >> 3;
    int wg = (xcd < r8 ? xcd * (q8 + 1) : r8 * (q8 + 1) + (xcd - r8) * q8) + lin;
    int per_group = GM * ntn;
    int g = wg / per_group, rem = wg - g * per_group;
    int gmrows = ntm - g * GM; if (gmrows > GM) gmrows = GM;
    int brow = g * GM + rem % gmrows;
    int bcol = rem / gmrows;
    int row0 = brow << 7, col0 = bcol << 7;

    int wm = w >> 1, wn = w & 1;              // 2x2 wave grid, 64x64 each

    // --- staging addressing (wave w stages rows 32w..32w+31 of As and Bs) ---
    int srow = 32 * w + (l >> 2);             // source row within tile
    int achk = (l & 3) << 3;                  // 16B chunk (f16 units)
    const f16* Abase = A  + (size_t)(row0 + srow) * 768  + achk;
    const f16* Bbase = Bt + (size_t)(col0 + srow) * 1536 + achk;
    int lw = 32 * w * 32;                     // wave LDS base (f16 units)

    f32x4 zz = {0.f, 0.f, 0.f, 0.f};
    f32x4 acc[4][4];
    #pragma unroll
    for (int i = 0; i < 4; ++i)
        #pragma unroll
        for (int j = 0; j < 4; ++j) acc[i][j] = zz;

    #define STAGE(bufi, kkv, bov)                                  \
        {                                                          \
            const f16* ga = Abase + (kkv);                         \
            const f16* gb = Bbase + (bov);                         \
            f16* la = &lds[(bufi)*8192 + lw];                      \
            f16* lb = &lds[(bufi)*8192 + 4096 + lw];               \
            gload16(ga,             la);                           \
            gload16(ga + 16*768,    la + 512);                     \
            gload16(gb,             lb);                           \
            gload16(gb + 16*1536,   lb + 512);                     \
        }

    STAGE(0, 0, 0);
    asm volatile("s_waitcnt vmcnt(0)" ::: "memory");
    __syncthreads();

    int buf = 0;
    int rbA = wm * 64 + (l & 15);
    int rbB = wn * 64 + (l & 15);
    int coff = (l >> 4) << 3;
    for (int s = 0; s < nsteps; ++s) {
        int sn = s + 1;
        if (sn < nsteps) {
            int kkn = (sn % 24) * 32;
            int bon = (sn < 24 ? 0 : boff1) + kkn;
            STAGE(buf ^ 1, kkn, bon);
        }
        const f16* Lb = &lds[buf * 8192];
        f16x8 af[4], bf[4];
        #pragma unroll
        for (int i = 0; i < 4; ++i)
            af[i] = *(const f16x8*)&Lb[(rbA + i*16) * 32 + coff];
        #pragma unroll
        for (int j = 0; j < 4; ++j)
            bf[j] = *(const f16x8*)&Lb[4096 + (rbB + j*16) * 32 + coff];
        #pragma unroll
        for (int i = 0; i < 4; ++i)
            #pragma unroll
            for (int j = 0; j < 4; ++j)
                acc[i][j] = __builtin_amdgcn_mfma_f32_16x16x32_f16(af[i], bf[j], acc[i][j], 0, 0, 0);
        asm volatile("s_waitcnt vmcnt(0)" ::: "memory");
        __syncthreads();
        buf ^= 1;
    }
    #undef STAGE

    // epilogue: D lane map col=l&15, row=(l>>4)*4+r  [m89/m91-verified]
    #pragma unroll
    for (int i = 0; i < 4; ++i) {
        #pragma unroll
        for (int j = 0; j < 4; ++j) {
            int gc = col0 + wn*64 + j*16 + (l & 15);
            #pragma unroll
            for (int r = 0; r < 4; ++r) {
                int gr = row0 + wm*64 + i*16 + (l >> 4) * 4 + r;
                if (gr < MV) {
                    size_t off = (size_t)gr * Nc + gc;
                    float v = acc[i][j][r];
                    if (ACC) C[off] += v;
                    else     C[off] = bias ? v + bias[gc] : v;
                }
            }
        }
    }
}

// ---------- per-(b,h,d) max & sum(exp) of K over tokens; also zero-inits kTv ----------
__global__ __launch_bounds__(256) void kstats_kernel(const float* __restrict__ qkv,
                                                     float* __restrict__ kmax,
                                                     float* __restrict__ ksum,
                                                     float* __restrict__ kTv) {
    int bh = blockIdx.x;
    int b = bh / NH, h = bh % NH;
    int t = threadIdx.x;
    for (int i = t; i < 4096; i += 256) kTv[(size_t)bh*4096 + i] = 0.f;
    int d = t & 63, slice = t >> 6;
    __shared__ float red[4][64];
    float m = -1e30f;
    for (int n = slice; n < NN; n += 4)
        m = fmaxf(m, qkv[(size_t)(b*NN + n)*2304 + 768 + h*64 + d]);
    red[slice][d] = m;
    __syncthreads();
    float mAll = fmaxf(fmaxf(red[0][d], red[1][d]), fmaxf(red[2][d], red[3][d]));
    __syncthreads();
    float s = 0.f;
    for (int n = slice; n < NN; n += 4)
        s += __expf(qkv[(size_t)(b*NN + n)*2304 + 768 + h*64 + d] - mAll);
    red[slice][d] = s;
    __syncthreads();
    if (slice == 0) {
        kmax[bh*64 + d] = mAll;
        ksum[bh*64 + d] = red[0][d] + red[1][d] + red[2][d] + red[3][d];
    }
}

// ---------- kTv[b,h] += partial softmax(K)^T @ V over a token chunk (atomic) ----------
__global__ __launch_bounds__(256) void ktv_kernel(const float* __restrict__ qkv,
                                                  const float* __restrict__ kmax,
                                                  const float* __restrict__ ksum,
                                                  float* __restrict__ kTv) {
    int bh = blockIdx.x;
    int chunk = blockIdx.y;
    int b = bh / NH, h = bh % NH;
    int t = threadIdx.x;
    int d = t & 63, slice = t >> 6;
    __shared__ float sk[4][64];
    __shared__ float sv[4][64];
    __shared__ float smax[64];
    if (t < 64) smax[t] = kmax[bh*64 + t];
    __syncthreads();
    float acc[16] = {};
    int vg = slice * 16;
    int nstart = chunk * 128;
    int nend = (chunk == 7) ? NN : (nstart + 128);
    for (int n0 = nstart; n0 < nend; n0 += 4) {
        int n = n0 + slice;
        float ek = 0.f, vv = 0.f;
        if (n < nend) {
            const float* row = qkv + (size_t)(b*NN + n) * 2304;
            ek = __expf(row[768 + h*64 + d] - smax[d]);
            vv = row[1536 + h*64 + d];
        }
        sk[slice][d] = ek;
        sv[slice][d] = vv;
        __syncthreads();
        #pragma unroll
        for (int s = 0; s < 4; ++s) {
            float e = sk[s][d];
            #pragma unroll
            for (int j = 0; j < 16; ++j)
                acc[j] = fmaf(e, sv[s][vg + j], acc[j]);
        }
        __syncthreads();
    }
    float inv = 1.0f / ksum[bh*64 + d];
    #pragma unroll
    for (int j = 0; j < 16; ++j)
        atomicAdd(&kTv[(size_t)bh*4096 + (size_t)d*64 + vg + j], acc[j] * inv);
}

// ---------- attn = scale*(q@kTv) + ev_hat, written into qkv's dead K-columns ----------
__global__ __launch_bounds__(256) void attn_kernel(float* qkv,
                                                   const float* __restrict__ kTv,
                                                   const float* __restrict__ crpe_w,
                                                   const float* __restrict__ crpe_b) {
    int tile = blockIdx.x;
    int nt = tile % 65;
    int bh = tile / 65;
    int b = bh / NH, h = bh % NH;
    __shared__ float sKT[64][64];
    __shared__ float sq[16][68];
    int t = threadIdx.x;
    for (int i = t; i < 4096; i += 256)
        sKT[i >> 6][i & 63] = kTv[(size_t)bh*4096 + i];
    int tt = t >> 4;
    int dd = (t & 15) << 2;
    int n = nt * 16 + tt;
    float4 qv = make_float4(0,0,0,0);
    if (n < NN) qv = *(const float4*)(qkv + (size_t)(b*NN + n)*2304 + h*64 + dd);
    sq[tt][dd+0] = qv.x; sq[tt][dd+1] = qv.y;
    sq[tt][dd+2] = qv.z; sq[tt][dd+3] = qv.w;
    __syncthreads();
    float o0=0.f, o1=0.f, o2=0.f, o3=0.f;
    #pragma unroll
    for (int k = 0; k < 64; ++k) {
        float qk = sq[tt][k];
        float4 kt = *(const float4*)&sKT[k][dd];
        o0 = fmaf(qk, kt.x, o0); o1 = fmaf(qk, kt.y, o1);
        o2 = fmaf(qk, kt.z, o2); o3 = fmaf(qk, kt.w, o3);
    }
    if (n < NN) {
        float res[4] = {0.125f*o0, 0.125f*o1, 0.125f*o2, 0.125f*o3};
        if (n >= 1) {
            int np = n - 1;
            #pragma unroll
            for (int j = 0; j < 4; ++j) {
                int d = dd + j;
                int g = h*65536 + np*64 + d;
                int y = g / 24576;
                int r1 = g - y*24576;
                int x = r1 / 768;
                int c = r1 - x*768;
                int hs = c >> 6;
                int c64 = c & 63;
                int ns = c64*16 + (y >> 1);
                int ds = ((y & 1) << 5) + x;
                float vsrc = qkv[(size_t)(b*NN + 1 + ns)*2304 + 1536 + hs*64 + ds];
                float conv = fmaf(vsrc, crpe_w[c], crpe_b[c]);
                res[j] = fmaf(sq[tt][d], conv, res[j]);
            }
        }
        // flat (B,nh,N,dh) index, remapped into qkv K-columns: row=f/768, col=768+f%768
        size_t f = (size_t)b*787200 + (size_t)h*65600 + (size_t)n*64 + dd;
        size_t adr = (f / 768) * 2304 + 768 + (f % 768);
        float4 r4 = make_float4(res[0], res[1], res[2], res[3]);
        *(float4*)&qkv[adr] = r4;
    }
}

extern "C" void kernel_launch(void* const* d_in, const int* in_sizes, int n_in,
                              void* d_out, int out_size, void* d_ws, size_t ws_size,
                              hipStream_t stream) {
    const float* inputs = (const float*)d_in[0];
    const float* cpe_w  = (const float*)d_in[1];
    const float* cpe_b  = (const float*)d_in[2];
    const float* w_qkv  = (const float*)d_in[3];
    const float* crpe_w = (const float*)d_in[4];
    const float* crpe_b = (const float*)d_in[5];
    const float* w_proj = (const float*)d_in[6];
    const float* b_proj = (const float*)d_in[7];
    float* out = (float*)d_out;
    float* ws  = (float*)d_ws;

    // ws layout (floats), total 45,895,680 f = 183.6 MB (< 204.8 MB proven-safe):
    f16*   Ah   = (f16*)ws;               // 16512*768 halves = 6,340,608 f
    float* qkv  = ws + 6340608;           // 16400*2304        = 37,785,600 f (K-cols reused for attn out)
    float* aux  = ws + 44126208;          // 1,769,472 f region:
    f16*   BpT1 = (f16*)aux;              //   GEMM1: 2304*1536 halves
    float* kTv  = aux;                    //   after GEMM1: 786,432 f
    float* kmax = aux + 786432;           //   12,288 f
    float* ksum = aux + 798720;           //   12,288 f
    f16*   BpT2 = (f16*)(aux + 811008);   //   768*1536 halves = 589,824 f

    // ---- GEMM1: qkv = pe @ w_qkv  (fp16 split: AhiBhi + AhiBlo, then += AloBhi) ----
    packBT<<<dim3(24, 72), 256, 0, stream>>>(w_qkv, BpT1, 2304);
    packA_cpe<0><<<MPAD, 192, 0, stream>>>(inputs, cpe_w, cpe_b, Ah);
    gemm_mfma<0><<<129*18, 256, 0, stream>>>(Ah, BpT1, nullptr, qkv, 2304, 48, 768);
    packA_cpe<1><<<MPAD, 192, 0, stream>>>(inputs, cpe_w, cpe_b, Ah);
    gemm_mfma<1><<<129*18, 256, 0, stream>>>(Ah, BpT1, nullptr, qkv, 2304, 24, 0);

    // ---- factorized attention ----
    kstats_kernel<<<BB*NH, 256, 0, stream>>>(qkv, kmax, ksum, kTv);
    ktv_kernel<<<dim3(BB*NH, 8), 256, 0, stream>>>(qkv, kmax, ksum, kTv);
    attn_kernel<<<BB*NH*65, 256, 0, stream>>>(qkv, kTv, crpe_w, crpe_b);

    // ---- GEMM2: out = attn @ w_proj + b_proj ----
    packBT<<<dim3(24, 24), 256, 0, stream>>>(w_proj, BpT2, 768);
    packA_attn<0><<<MPAD, 192, 0, stream>>>(qkv, Ah);
    gemm_mfma<0><<<129*6, 256, 0, stream>>>(Ah, BpT2, b_proj, out, 768, 48, 768);
    packA_attn<1><<<MPAD, 192, 0, stream>>>(qkv, Ah);
    gemm_mfma<1><<<129*6, 256, 0, stream>>>(Ah, BpT2, nullptr, out, 768, 24, 0);
}